// Round 4
// baseline (798.743 us; speedup 1.0000x reference)
//
#include <hip/hip_runtime.h>
#include <cmath>

#define N_TOK 4096
#define DDIM 1024
#define FDIM 4096
#define NEXP 8
#define MAXT 40                 // 256-row tiles; worst case sum ceil(c_e/256) = 39
#define MAXROWS (MAXT * 256)

typedef __attribute__((ext_vector_type(4))) float f32x4;
typedef __attribute__((ext_vector_type(8))) __bf16 bf16x8;
typedef __attribute__((ext_vector_type(4))) unsigned short us4;
typedef __attribute__((ext_vector_type(8))) unsigned short us8;

__device__ __forceinline__ unsigned short f2bf(float f) {
  unsigned u = __builtin_bit_cast(unsigned, f);
  u += 0x7FFFu + ((u >> 16) & 1u);
  return (unsigned short)(u >> 16);
}

__device__ __forceinline__ void gload16(const void* g, void* l) {
  __builtin_amdgcn_global_load_lds(
      (const __attribute__((address_space(1))) unsigned int*)g,
      (__attribute__((address_space(3))) unsigned int*)l, 16, 0, 0);
}

// m204 bijective XCD remap
__device__ __forceinline__ int xcd_remap(int h, int nwg) {
  int q = nwg >> 3, r = nwg & 7;
  int xcd = h & 7, o = h >> 3;
  return (xcd < r ? xcd * (q + 1) : r * (q + 1) + (xcd - r) * q) + o;
}

// ---------------- router ----------------
__global__ __launch_bounds__(64) void router_kernel(
    const float* __restrict__ x, const float* __restrict__ wg,
    float* __restrict__ probs, int* __restrict__ eids, float* __restrict__ ewts) {
  int n = blockIdx.x;
  int t = threadIdx.x;
  const float* xr = x + (size_t)n * DDIM;
  float acc[8] = {0, 0, 0, 0, 0, 0, 0, 0};
  for (int k = t; k < DDIM; k += 64) {
    float xv = xr[k];
    const float* wr = wg + k * 8;
#pragma unroll
    for (int e = 0; e < 8; e++) acc[e] = fmaf(xv, wr[e], acc[e]);
  }
#pragma unroll
  for (int off = 32; off > 0; off >>= 1) {
#pragma unroll
    for (int e = 0; e < 8; e++) acc[e] += __shfl_xor(acc[e], off, 64);
  }
  if (t == 0) {
    float mx = acc[0];
#pragma unroll
    for (int e = 1; e < 8; e++) mx = fmaxf(mx, acc[e]);
    float p[8], s = 0.f;
#pragma unroll
    for (int e = 0; e < 8; e++) { p[e] = expf(acc[e] - mx); s += p[e]; }
    float inv = 1.f / s;
#pragma unroll
    for (int e = 0; e < 8; e++) { p[e] *= inv; probs[n * 8 + e] = p[e]; }
    int i0 = 0;
#pragma unroll
    for (int e = 1; e < 8; e++) if (p[e] > p[i0]) i0 = e;
    int i1 = (i0 == 0) ? 1 : 0;
#pragma unroll
    for (int e = 0; e < 8; e++) if (e != i0 && p[e] > p[i1]) i1 = e;
    float sw = p[i0] + p[i1];
    eids[n * 2] = i0; eids[n * 2 + 1] = i1;
    ewts[n * 2] = p[i0] / sw; ewts[n * 2 + 1] = p[i1] / sw;
  }
}

// ---------------- plan (256-row tiles) ----------------
__global__ __launch_bounds__(256) void plan_kernel(
    const float* __restrict__ probs, const int* __restrict__ eids,
    float* __restrict__ aux_out, int* __restrict__ meta) {
  __shared__ float pl[256][8];
  __shared__ int cl[256][8];
  __shared__ float ps2[8];
  __shared__ int cn2[8];
  int t = threadIdx.x;
  float pa[8] = {0, 0, 0, 0, 0, 0, 0, 0};
  int ca[8] = {0, 0, 0, 0, 0, 0, 0, 0};
  for (int n = t; n < N_TOK; n += 256) {
#pragma unroll
    for (int e = 0; e < 8; e++) pa[e] += probs[n * 8 + e];
    ca[eids[n * 2]]++; ca[eids[n * 2 + 1]]++;
  }
#pragma unroll
  for (int e = 0; e < 8; e++) { pl[t][e] = pa[e]; cl[t][e] = ca[e]; }
  __syncthreads();
  if (t < 8) {
    float s = 0; int c = 0;
    for (int i = 0; i < 256; i++) { s += pl[i][t]; c += cl[i][t]; }
    ps2[t] = s; cn2[t] = c;
  }
  __syncthreads();
  if (t == 0) {
    int tb = 0; float aux = 0.f;
    for (int e = 0; e < 8; e++) {
      int c = cn2[e];
      meta[e] = c; meta[8 + e] = 0; meta[16 + e] = tb;
      int tiles = (c + 255) >> 8;
      for (int i = 0; i < tiles; i++) meta[24 + tb + i] = e;
      tb += tiles;
      aux += ((float)c / (float)(N_TOK * 2)) * (ps2[e] / (float)N_TOK);
    }
    meta[96] = tb;
    *aux_out = 0.01f * 8.f * aux;
  }
}

// ---------------- scatter ----------------
__global__ __launch_bounds__(256) void scatter_kernel(
    const int* __restrict__ eids, const float* __restrict__ ewts,
    int* __restrict__ meta, int* __restrict__ perm, float* __restrict__ wgt) {
  int n = blockIdx.x * 256 + threadIdx.x;
  if (n >= N_TOK) return;
#pragma unroll
  for (int s = 0; s < 2; s++) {
    int e = eids[n * 2 + s];
    int pos = atomicAdd(&meta[8 + e], 1);
    int row = (meta[16 + e] << 8) + pos;
    perm[row] = n;
    wgt[row] = ewts[n * 2 + s];
  }
}

// ---------------- x f32 -> bf16 ----------------
__global__ __launch_bounds__(256) void convert_x_kernel(
    const float* __restrict__ x, unsigned short* __restrict__ xb) {
  int i = blockIdx.x * 256 + threadIdx.x;
  f32x4 v = ((const f32x4*)x)[i];
  us4 o = {f2bf(v[0]), f2bf(v[1]), f2bf(v[2]), f2bf(v[3])};
  ((us4*)xb)[i] = o;
}

// ---------------- transpose + convert f32[R][C] -> bf16[C][R] ----------------
__global__ __launch_bounds__(256) void transpose_conv(
    const float* __restrict__ src, unsigned short* __restrict__ dst, int R, int C) {
  __shared__ unsigned short tile[64 * 64];
  size_t eoff = (size_t)blockIdx.z * (size_t)R * (size_t)C;
  src += eoff; dst += eoff;
  int c0 = blockIdx.x << 6, r0 = blockIdx.y << 6;
  int t = threadIdx.x;
  int rl = (t >> 4) << 2;
  int cl = (t & 15) << 2;
  f32x4 v[4];
#pragma unroll
  for (int i = 0; i < 4; i++)
    v[i] = *(const f32x4*)(src + (size_t)(r0 + rl + i) * C + c0 + cl);
#pragma unroll
  for (int u = 0; u < 4; u++) {
    int c = cl + u;
    us4 o = {f2bf(v[0][u]), f2bf(v[1][u]), f2bf(v[2][u]), f2bf(v[3][u])};
    unsigned byteoff = (unsigned)c * 128 + ((((unsigned)(rl >> 3)) ^ (unsigned)(c & 7)) << 4) + (unsigned)(rl & 7) * 2;
    *(us4*)((char*)tile + byteoff) = o;
  }
  __syncthreads();
#pragma unroll
  for (int p = 0; p < 2; p++) {
    int id = t + p * 256;
    int c = id >> 3, q = id & 7;
    unsigned byteoff = (unsigned)c * 128 + (((unsigned)q ^ (unsigned)(c & 7)) << 4);
    us8 val = *(const us8*)((const char*)tile + byteoff);
    *(us8*)(dst + (size_t)(c0 + c) * R + r0 + q * 8) = val;
  }
}

// ============ 256x256 grouped GEMM, 4 quadrant-phases/K-tile, counted vmcnt ============
// 8 waves (2M x 4N). Per phase ALL waves compute ONE global 128x128 output quadrant,
// reading exactly one A-half + one B-half from LDS. Halves of tile t+1 staged one
// per phase (order a0,b0,a1,b1) into the other buffer; waits are counted (never 0
// in steady state): P1/P2/P4 vmcnt(4). Quadrant order (0,0)->(1,0)->(1,1)->(0,1).
// LDS 128 KiB: 2 bufs x [A 32K | B 32K], XOR-swizzle via pre-swizzled global source.
// MODE 1: gelu->bf16 Hout.  MODE 2: weighted f32 atomic scatter into Out.

#define DS_A(QM)                                                               \
  _Pragma("unroll") for (int mf = 0; mf < 4; mf++)                             \
  _Pragma("unroll") for (int kss = 0; kss < 2; kss++) {                        \
    int m = (QM)*128 + wm * 64 + mf * 16 + ln;                                 \
    af[mf][kss] = *(const bf16x8*)(bc + m * 128 + ((((kss * 4) + g) ^ (m & 7)) << 4)); \
  }

#define DS_B(QN)                                                               \
  _Pragma("unroll") for (int nf = 0; nf < 2; nf++)                             \
  _Pragma("unroll") for (int kss = 0; kss < 2; kss++) {                        \
    int nn = (QN)*128 + wn * 32 + nf * 16 + ln;                                \
    bfr[nf][kss] = *(const bf16x8*)(bc + 32768 + nn * 128 + ((((kss * 4) + g) ^ (nn & 7)) << 4)); \
  }

#define MFMA_Q(Q)                                                              \
  __builtin_amdgcn_s_setprio(1);                                              \
  _Pragma("unroll") for (int mf = 0; mf < 4; mf++)                             \
  _Pragma("unroll") for (int nf = 0; nf < 2; nf++)                             \
  _Pragma("unroll") for (int kss = 0; kss < 2; kss++)                          \
    acc[Q][mf][nf] = __builtin_amdgcn_mfma_f32_16x16x32_bf16(                  \
        af[mf][kss], bfr[nf][kss], acc[Q][mf][nf], 0, 0, 0);                   \
  __builtin_amdgcn_s_setprio(0);

#define STAGE(H, KO, DST)                                                      \
  gload16(src[H][0] + (KO), (DST) + loff[H][0]);                               \
  gload16(src[H][1] + (KO), (DST) + loff[H][1]);

#define WAITVM(N) asm volatile("s_waitcnt vmcnt(" #N ")" ::: "memory")
#define LGKM0                                                                  \
  asm volatile("s_waitcnt lgkmcnt(0)" ::: "memory");                           \
  __builtin_amdgcn_sched_barrier(0);
#define BAR __builtin_amdgcn_s_barrier()

template <int K, int KSLICES, int NPANELS, bool GATHER, int MODE>
__global__ __launch_bounds__(512, 2) void gemm8p(
    const unsigned short* __restrict__ A,   // bf16 rows, stride K
    const unsigned short* __restrict__ Bt,  // bf16 [E][NB][K]
    unsigned short* __restrict__ Hout,
    float* __restrict__ Out,
    const int* __restrict__ perm, const float* __restrict__ wgt,
    const int* __restrict__ tileExpert, const int* __restrict__ totalTiles,
    int NB) {
  constexpr int NWG = MAXT * NPANELS * KSLICES;
  constexpr int KB = K / KSLICES;
  constexpr int NT = KB / 64;
  __shared__ unsigned short smem[65536];  // 128 KiB

  int L = xcd_remap((int)blockIdx.x, NWG);
  constexpr int PER = NPANELS * KSLICES;
  int mt = L / PER;
  int rest = L % PER;
  int nt = rest % NPANELS;
  int ks = rest / NPANELS;
  if (mt >= *totalTiles) return;
  int e = tileExpert[mt];
  int m0 = mt << 8, n0 = nt << 8, k0 = ks * KB;

  int t = threadIdx.x;
  int wid = t >> 6, lane = t & 63;
  int g = lane >> 4, ln = lane & 15;
  int wm = wid >> 2, wn = wid & 3;

  // halves: 0=A[0:128) 1=B[0:128) 2=A[128:256) 3=B[128:256)
  const unsigned short* src[4][2];
  unsigned loff[4][2];
  {
    int kc = lane & 7;
#pragma unroll
    for (int l = 0; l < 2; l++) {
      int r8 = l * 64 + wid * 8 + (lane >> 3);
      unsigned cb = (unsigned)(l * 512 + wid * 64) * 16u;
      int swz = ((kc ^ (r8 & 7)) << 3);
      int ga0 = GATHER ? perm[m0 + r8] : (m0 + r8);
      int ga1 = GATHER ? perm[m0 + 128 + r8] : (m0 + 128 + r8);
      src[0][l] = A + (size_t)ga0 * K + k0 + swz;
      loff[0][l] = cb;
      src[2][l] = A + (size_t)ga1 * K + k0 + swz;
      loff[2][l] = 16384u + cb;
      src[1][l] = Bt + ((size_t)e * NB + n0 + r8) * K + k0 + swz;
      loff[1][l] = 32768u + cb;
      src[3][l] = Bt + ((size_t)e * NB + n0 + 128 + r8) * K + k0 + swz;
      loff[3][l] = 49152u + cb;
    }
  }

  f32x4 acc[4][4][2];
#pragma unroll
  for (int a = 0; a < 4; a++)
#pragma unroll
    for (int b = 0; b < 4; b++)
#pragma unroll
      for (int c = 0; c < 2; c++) acc[a][b][c] = (f32x4){0.f, 0.f, 0.f, 0.f};

  bf16x8 af[4][2], bfr[2][2];
  char* smb = (char*)smem;

  // prologue: stage all 4 halves of tile 0 into buf0 (issue order 0,1,2,3)
  STAGE(0, 0, smb) STAGE(1, 0, smb) STAGE(2, 0, smb) STAGE(3, 0, smb)
  WAITVM(4);  // a0,b0 landed; a1,b1 (4 loads) in flight
  BAR;

  for (int tt = 0; tt < NT - 1; ++tt) {
    const char* bc = smb + (tt & 1) * 65536;
    char* bd = smb + (((tt & 1) ^ 1) * 65536);
    int ko = (tt + 1) * 64;

    // P1: quadrant (0,0) reads a0,b0; stage a0(t+1)
    DS_A(0) DS_B(0)
    STAGE(0, ko, bd)
    WAITVM(4);  // retire a1(t) for P2
    BAR; LGKM0
    MFMA_Q(0)
    BAR;

    // P2: quadrant (1,0) reads a1,(b0 in regs); stage b0(t+1)
    DS_A(1)
    STAGE(1, ko, bd)
    WAITVM(4);  // retire b1(t) for P3
    BAR; LGKM0
    MFMA_Q(1)
    BAR;

    // P3: quadrant (1,1) reads (a1 in regs),b1; stage a1(t+1); no wait
    DS_B(1)
    STAGE(2, ko, bd)
    BAR; LGKM0
    MFMA_Q(2)
    BAR;

    // P4: quadrant (0,1) reads a0,(b1 in regs); stage b1(t+1)
    DS_A(0)
    STAGE(3, ko, bd)
    WAITVM(4);  // retire a0(t+1),b0(t+1) for next P1
    BAR; LGKM0
    MFMA_Q(3)
    BAR;
  }

  // peeled last tile: drain 4 -> 2 -> 0
  {
    const char* bc = smb + ((NT - 1) & 1) * 65536;
    DS_A(0) DS_B(0)
    WAITVM(2);
    BAR; LGKM0
    MFMA_Q(0)
    BAR;
    DS_A(1)
    WAITVM(0);
    BAR; LGKM0
    MFMA_Q(1)
    BAR;
    DS_B(1)
    BAR; LGKM0
    MFMA_Q(2)
    BAR;
    DS_A(0)
    LGKM0
    MFMA_Q(3)
  }

  // epilogue: quadrant q -> (qm, qn); C/D map col=ln, row=g*4+rr
#pragma unroll
  for (int qq = 0; qq < 4; qq++) {
    int qm = (qq == 1 || qq == 2) ? 1 : 0;
    int qn = (qq >= 2) ? 1 : 0;
#pragma unroll
    for (int mf = 0; mf < 4; mf++) {
      int rowb = m0 + qm * 128 + wm * 64 + mf * 16 + g * 4;
#pragma unroll
      for (int nf = 0; nf < 2; nf++) {
        int col = n0 + qn * 128 + wn * 32 + nf * 16 + ln;
#pragma unroll
        for (int rr = 0; rr < 4; rr++) {
          float v = acc[qq][mf][nf][rr];
          if (MODE == 1) {
            v = 0.5f * v * (1.f + erff(v * 0.70710678118654752f));
            Hout[(size_t)(rowb + rr) * NB + col] = f2bf(v);
          } else {
            int pr = rowb + rr;
            atomicAdd(Out + (size_t)perm[pr] * NB + col, wgt[pr] * v);
          }
        }
      }
    }
  }
}

extern "C" void kernel_launch(void* const* d_in, const int* in_sizes, int n_in,
                              void* d_out, int out_size, void* d_ws, size_t ws_size,
                              hipStream_t stream) {
  const float* x = (const float*)d_in[0];
  const float* wgate = (const float*)d_in[1];
  const float* w1 = (const float*)d_in[2];
  const float* w2 = (const float*)d_in[3];
  float* out = (float*)d_out;

  char* w = (char*)d_ws;
  float* probs = (float*)w;                 w += (size_t)N_TOK * 8 * 4;
  int* eids = (int*)w;                      w += (size_t)N_TOK * 2 * 4;
  float* ewts = (float*)w;                  w += (size_t)N_TOK * 2 * 4;
  int* meta = (int*)w;                      w += 512;
  int* perm = (int*)w;                      w += (size_t)MAXROWS * 4;
  float* pwgt = (float*)w;                  w += (size_t)MAXROWS * 4;
  unsigned short* xb = (unsigned short*)w;  w += (size_t)N_TOK * DDIM * 2;
  unsigned short* w1t = (unsigned short*)w; w += (size_t)NEXP * DDIM * FDIM * 2;
  unsigned short* w2t = (unsigned short*)w; w += (size_t)NEXP * DDIM * FDIM * 2;
  unsigned short* h = (unsigned short*)w;   w += (size_t)MAXROWS * FDIM * 2;

  hipMemsetAsync(d_out, 0, (size_t)out_size * 4, stream);
  hipMemsetAsync(perm, 0, (size_t)MAXROWS * 8, stream);  // perm + pwgt (adjacent)

  router_kernel<<<N_TOK, 64, 0, stream>>>(x, wgate, probs, eids, ewts);
  plan_kernel<<<1, 256, 0, stream>>>(probs, eids, out + 4194304, meta);
  scatter_kernel<<<16, 256, 0, stream>>>(eids, ewts, meta, perm, pwgt);
  convert_x_kernel<<<4096, 256, 0, stream>>>(x, xb);
  transpose_conv<<<dim3(64, 16, 8), 256, 0, stream>>>(w1, w1t, DDIM, FDIM);
  transpose_conv<<<dim3(16, 64, 8), 256, 0, stream>>>(w2, w2t, FDIM, DDIM);
  // GEMM1: rows x [1024] @ [1024 x 4096]/expert -> h (gelu, bf16). 40x16 tiles.
  gemm8p<DDIM, 1, 16, true, 1><<<MAXT * 16, 512, 0, stream>>>(
      xb, w1t, h, nullptr, perm, pwgt, meta + 24, meta + 96, FDIM);
  // GEMM2: rows x [4096] @ [4096 x 1024]/expert, split-K=4 -> atomic f32 out.
  gemm8p<FDIM, 4, 4, false, 2><<<MAXT * 16, 512, 0, stream>>>(
      h, w2t, nullptr, out, perm, pwgt, meta + 24, meta + 96, DDIM);
}

// Round 5
// 714.636 us; speedup vs baseline: 1.1177x; 1.1177x over previous
//
#include <hip/hip_runtime.h>
#include <cmath>

#define N_TOK 4096
#define DDIM 1024
#define FDIM 4096
#define NEXP 8
#define MAXT 40                 // 256-row tiles; worst case sum ceil(c_e/256) = 39
#define MAXROWS (MAXT * 256)

typedef __attribute__((ext_vector_type(4))) float f32x4;
typedef __attribute__((ext_vector_type(8))) __bf16 bf16x8;
typedef __attribute__((ext_vector_type(4))) unsigned short us4;
typedef __attribute__((ext_vector_type(8))) unsigned short us8;

__device__ __forceinline__ unsigned short f2bf(float f) {
  unsigned u = __builtin_bit_cast(unsigned, f);
  u += 0x7FFFu + ((u >> 16) & 1u);
  return (unsigned short)(u >> 16);
}

__device__ __forceinline__ void gload16(const void* g, void* l) {
  __builtin_amdgcn_global_load_lds(
      (const __attribute__((address_space(1))) unsigned int*)g,
      (__attribute__((address_space(3))) unsigned int*)l, 16, 0, 0);
}

// m204 bijective XCD remap
__device__ __forceinline__ int xcd_remap(int h, int nwg) {
  int q = nwg >> 3, r = nwg & 7;
  int xcd = h & 7, o = h >> 3;
  return (xcd < r ? xcd * (q + 1) : r * (q + 1) + (xcd - r) * q) + o;
}

// ---------------- router ----------------
__global__ __launch_bounds__(64) void router_kernel(
    const float* __restrict__ x, const float* __restrict__ wg,
    float* __restrict__ probs, int* __restrict__ eids, float* __restrict__ ewts) {
  int n = blockIdx.x;
  int t = threadIdx.x;
  const float* xr = x + (size_t)n * DDIM;
  float acc[8] = {0, 0, 0, 0, 0, 0, 0, 0};
  for (int k = t; k < DDIM; k += 64) {
    float xv = xr[k];
    const float* wr = wg + k * 8;
#pragma unroll
    for (int e = 0; e < 8; e++) acc[e] = fmaf(xv, wr[e], acc[e]);
  }
#pragma unroll
  for (int off = 32; off > 0; off >>= 1) {
#pragma unroll
    for (int e = 0; e < 8; e++) acc[e] += __shfl_xor(acc[e], off, 64);
  }
  if (t == 0) {
    float mx = acc[0];
#pragma unroll
    for (int e = 1; e < 8; e++) mx = fmaxf(mx, acc[e]);
    float p[8], s = 0.f;
#pragma unroll
    for (int e = 0; e < 8; e++) { p[e] = expf(acc[e] - mx); s += p[e]; }
    float inv = 1.f / s;
#pragma unroll
    for (int e = 0; e < 8; e++) { p[e] *= inv; probs[n * 8 + e] = p[e]; }
    int i0 = 0;
#pragma unroll
    for (int e = 1; e < 8; e++) if (p[e] > p[i0]) i0 = e;
    int i1 = (i0 == 0) ? 1 : 0;
#pragma unroll
    for (int e = 0; e < 8; e++) if (e != i0 && p[e] > p[i1]) i1 = e;
    float sw = p[i0] + p[i1];
    eids[n * 2] = i0; eids[n * 2 + 1] = i1;
    ewts[n * 2] = p[i0] / sw; ewts[n * 2 + 1] = p[i1] / sw;
  }
}

// ---------------- plan (256-row tiles) ----------------
__global__ __launch_bounds__(256) void plan_kernel(
    const float* __restrict__ probs, const int* __restrict__ eids,
    float* __restrict__ aux_out, int* __restrict__ meta) {
  __shared__ float pl[256][8];
  __shared__ int cl[256][8];
  __shared__ float ps2[8];
  __shared__ int cn2[8];
  int t = threadIdx.x;
  float pa[8] = {0, 0, 0, 0, 0, 0, 0, 0};
  int ca[8] = {0, 0, 0, 0, 0, 0, 0, 0};
  for (int n = t; n < N_TOK; n += 256) {
#pragma unroll
    for (int e = 0; e < 8; e++) pa[e] += probs[n * 8 + e];
    ca[eids[n * 2]]++; ca[eids[n * 2 + 1]]++;
  }
#pragma unroll
  for (int e = 0; e < 8; e++) { pl[t][e] = pa[e]; cl[t][e] = ca[e]; }
  __syncthreads();
  if (t < 8) {
    float s = 0; int c = 0;
    for (int i = 0; i < 256; i++) { s += pl[i][t]; c += cl[i][t]; }
    ps2[t] = s; cn2[t] = c;
  }
  __syncthreads();
  if (t == 0) {
    int tb = 0; float aux = 0.f;
    for (int e = 0; e < 8; e++) {
      int c = cn2[e];
      meta[e] = c; meta[8 + e] = 0; meta[16 + e] = tb;
      int tiles = (c + 255) >> 8;
      for (int i = 0; i < tiles; i++) meta[24 + tb + i] = e;
      tb += tiles;
      aux += ((float)c / (float)(N_TOK * 2)) * (ps2[e] / (float)N_TOK);
    }
    meta[96] = tb;
    *aux_out = 0.01f * 8.f * aux;
  }
}

// ---------------- scatter ----------------
__global__ __launch_bounds__(256) void scatter_kernel(
    const int* __restrict__ eids, const float* __restrict__ ewts,
    int* __restrict__ meta, int* __restrict__ perm, float* __restrict__ wgt) {
  int n = blockIdx.x * 256 + threadIdx.x;
  if (n >= N_TOK) return;
#pragma unroll
  for (int s = 0; s < 2; s++) {
    int e = eids[n * 2 + s];
    int pos = atomicAdd(&meta[8 + e], 1);
    int row = (meta[16 + e] << 8) + pos;
    perm[row] = n;
    wgt[row] = ewts[n * 2 + s];
  }
}

// ---------------- x f32 -> bf16 ----------------
__global__ __launch_bounds__(256) void convert_x_kernel(
    const float* __restrict__ x, unsigned short* __restrict__ xb) {
  int i = blockIdx.x * 256 + threadIdx.x;
  f32x4 v = ((const f32x4*)x)[i];
  us4 o = {f2bf(v[0]), f2bf(v[1]), f2bf(v[2]), f2bf(v[3])};
  ((us4*)xb)[i] = o;
}

// ---------------- transpose + convert f32[R][C] -> bf16[C][R] ----------------
__global__ __launch_bounds__(256) void transpose_conv(
    const float* __restrict__ src, unsigned short* __restrict__ dst, int R, int C) {
  __shared__ unsigned short tile[64 * 64];
  size_t eoff = (size_t)blockIdx.z * (size_t)R * (size_t)C;
  src += eoff; dst += eoff;
  int c0 = blockIdx.x << 6, r0 = blockIdx.y << 6;
  int t = threadIdx.x;
  int rl = (t >> 4) << 2;
  int cl = (t & 15) << 2;
  f32x4 v[4];
#pragma unroll
  for (int i = 0; i < 4; i++)
    v[i] = *(const f32x4*)(src + (size_t)(r0 + rl + i) * C + c0 + cl);
#pragma unroll
  for (int u = 0; u < 4; u++) {
    int c = cl + u;
    us4 o = {f2bf(v[0][u]), f2bf(v[1][u]), f2bf(v[2][u]), f2bf(v[3][u])};
    unsigned byteoff = (unsigned)c * 128 + ((((unsigned)(rl >> 3)) ^ (unsigned)(c & 7)) << 4) + (unsigned)(rl & 7) * 2;
    *(us4*)((char*)tile + byteoff) = o;
  }
  __syncthreads();
#pragma unroll
  for (int p = 0; p < 2; p++) {
    int id = t + p * 256;
    int c = id >> 3, q = id & 7;
    unsigned byteoff = (unsigned)c * 128 + (((unsigned)q ^ (unsigned)(c & 7)) << 4);
    us8 val = *(const us8*)((const char*)tile + byteoff);
    *(us8*)(dst + (size_t)(c0 + c) * R + r0 + q * 8) = val;
  }
}

// ============ 256x256 grouped GEMM, 2-phase double-buffer, BK=64, 8 waves ============
// Per K-tile body: ds_read ALL fragments of current buffer FIRST (zero DMA
// outstanding -> no compiler-inserted vmcnt waits), THEN issue next tile's
// global_load_lds stage into the OTHER (distinct __shared__) buffer, then 64
// MFMAs (the stage flies under them), then ONE __syncthreads() (the mandatory
// drain lands exactly where a full drain is wanted). K-loop unrolled x2 so
// each body names fixed buffers. m230-pattern (682 TF refcheck'd).
// MODE 1: gelu->bf16 Hout.  MODE 2: weighted f32 atomic scatter into Out.

#define STAGE_AB(NA, NB_, ko)                                                  \
  _Pragma("unroll") for (int i = 0; i < 4; i++) {                              \
    gload16(srcA[i] + (ko), (char*)(NA) + ldsoff[i]);                          \
    gload16(srcB[i] + (ko), (char*)(NB_) + ldsoff[i]);                         \
  }

#define BODY(CA, CB, NA, NB_, ko, dostage)                                     \
  {                                                                            \
    bf16x8 bfr[4][2];                                                          \
    _Pragma("unroll") for (int nf = 0; nf < 4; nf++)                           \
    _Pragma("unroll") for (int kss = 0; kss < 2; kss++) {                      \
      int nn = wn * 64 + nf * 16 + ln;                                         \
      bfr[nf][kss] = *(const bf16x8*)((const char*)(CB) + nn * 128 +           \
                                      (((kss * 4 + g) ^ (nn & 7)) << 4));      \
    }                                                                          \
    bf16x8 afl[8][2];                                                          \
    _Pragma("unroll") for (int mf = 0; mf < 8; mf++) {                         \
      int m = wm * 128 + mf * 16 + ln;                                         \
      afl[mf][0] = *(const bf16x8*)((const char*)(CA) + m * 128 +              \
                                    ((g ^ (m & 7)) << 4));                     \
      afl[mf][1] = *(const bf16x8*)((const char*)(CA) + m * 128 +              \
                                    (((4 + g) ^ (m & 7)) << 4));               \
    }                                                                          \
    if (dostage) { STAGE_AB(NA, NB_, ko) }                                     \
    _Pragma("unroll") for (int mf = 0; mf < 8; mf++)                           \
    _Pragma("unroll") for (int nf = 0; nf < 4; nf++) {                         \
      acc[mf][nf] = __builtin_amdgcn_mfma_f32_16x16x32_bf16(                   \
          afl[mf][0], bfr[nf][0], acc[mf][nf], 0, 0, 0);                       \
      acc[mf][nf] = __builtin_amdgcn_mfma_f32_16x16x32_bf16(                   \
          afl[mf][1], bfr[nf][1], acc[mf][nf], 0, 0, 0);                       \
    }                                                                          \
    __syncthreads();                                                           \
  }

template <int K, int KSLICES, int NPANELS, bool GATHER, int MODE>
__global__ __launch_bounds__(512) void gemm2p(
    const unsigned short* __restrict__ A,   // bf16 rows, stride K
    const unsigned short* __restrict__ Bt,  // bf16 [E][NB][K]
    unsigned short* __restrict__ Hout,
    float* __restrict__ Out,
    const int* __restrict__ perm, const float* __restrict__ wgt,
    const int* __restrict__ tileExpert, const int* __restrict__ totalTiles,
    int NB) {
  constexpr int NWG = MAXT * NPANELS * KSLICES;
  constexpr int KB = K / KSLICES;
  constexpr int NT = KB / 64;  // 16 for both GEMMs
  static_assert(NT % 2 == 0, "NT must be even");
  __shared__ unsigned short bufA0[16384];  // 32 KB each; 128 KB total
  __shared__ unsigned short bufB0[16384];
  __shared__ unsigned short bufA1[16384];
  __shared__ unsigned short bufB1[16384];

  int L = xcd_remap((int)blockIdx.x, NWG);
  constexpr int PER = NPANELS * KSLICES;
  int mt = L / PER;
  int rest = L % PER;
  int nt = rest % NPANELS;
  int ks = rest / NPANELS;
  if (mt >= *totalTiles) return;
  int e = tileExpert[mt];
  int m0 = mt << 8, n0 = nt << 8, k0 = ks * KB;

  int t = threadIdx.x;
  int wid = t >> 6, lane = t & 63;
  int g = lane >> 4, ln = lane & 15;
  int wm = wid >> 2, wn = wid & 3;  // 2M x 4N waves; per-wave C = 128x64

  // staging sources: pass i covers rows [i*64, i*64+64); wave wid handles
  // rows i*64 + wid*8 + (lane>>3), k-chunk (lane&7), XOR-swizzle pre-applied
  // on the GLOBAL source (LDS dest stays linear: uniform base + lane*16).
  const unsigned short* srcA[4];
  const unsigned short* srcB[4];
  unsigned ldsoff[4];
  {
    int kc = lane & 7;
    int r8 = lane >> 3;  // 0..7 == row&7
    int swz = (kc ^ r8) << 3;
#pragma unroll
    for (int i = 0; i < 4; i++) {
      int row = i * 64 + wid * 8 + r8;
      int ga = GATHER ? perm[m0 + row] : (m0 + row);
      srcA[i] = A + (size_t)ga * K + k0 + swz;
      srcB[i] = Bt + ((size_t)e * NB + n0 + row) * K + k0 + swz;
      ldsoff[i] = (unsigned)(i * 64 + wid * 8) * 128u;
    }
  }

  f32x4 acc[8][4];
#pragma unroll
  for (int a = 0; a < 8; a++)
#pragma unroll
    for (int b = 0; b < 4; b++) acc[a][b] = (f32x4){0.f, 0.f, 0.f, 0.f};

  // prologue: stage K-tile 0 into buf0
  STAGE_AB(bufA0, bufB0, 0)
  __syncthreads();

  for (int p = 0; p < NT / 2; ++p) {
    int k1 = (2 * p + 1) * 64, k2 = (2 * p + 2) * 64;
    BODY(bufA0, bufB0, bufA1, bufB1, k1, true)
    BODY(bufA1, bufB1, bufA0, bufB0, k2, (2 * p + 2) < NT)
  }

  // epilogue: C/D map col=ln, row=g*4+rr per 16x16 fragment
#pragma unroll
  for (int mf = 0; mf < 8; mf++) {
    int rowb = m0 + wm * 128 + mf * 16 + g * 4;
#pragma unroll
    for (int nf = 0; nf < 4; nf++) {
      int col = n0 + wn * 64 + nf * 16 + ln;
#pragma unroll
      for (int rr = 0; rr < 4; rr++) {
        float v = acc[mf][nf][rr];
        if (MODE == 1) {
          v = 0.5f * v * (1.f + erff(v * 0.70710678118654752f));
          Hout[(size_t)(rowb + rr) * NB + col] = f2bf(v);
        } else {
          int pr = rowb + rr;
          atomicAdd(Out + (size_t)perm[pr] * NB + col, wgt[pr] * v);
        }
      }
    }
  }
}

extern "C" void kernel_launch(void* const* d_in, const int* in_sizes, int n_in,
                              void* d_out, int out_size, void* d_ws, size_t ws_size,
                              hipStream_t stream) {
  const float* x = (const float*)d_in[0];
  const float* wgate = (const float*)d_in[1];
  const float* w1 = (const float*)d_in[2];
  const float* w2 = (const float*)d_in[3];
  float* out = (float*)d_out;

  char* w = (char*)d_ws;
  float* probs = (float*)w;                 w += (size_t)N_TOK * 8 * 4;
  int* eids = (int*)w;                      w += (size_t)N_TOK * 2 * 4;
  float* ewts = (float*)w;                  w += (size_t)N_TOK * 2 * 4;
  int* meta = (int*)w;                      w += 512;
  int* perm = (int*)w;                      w += (size_t)MAXROWS * 4;
  float* pwgt = (float*)w;                  w += (size_t)MAXROWS * 4;
  unsigned short* xb = (unsigned short*)w;  w += (size_t)N_TOK * DDIM * 2;
  unsigned short* w1t = (unsigned short*)w; w += (size_t)NEXP * DDIM * FDIM * 2;
  unsigned short* w2t = (unsigned short*)w; w += (size_t)NEXP * DDIM * FDIM * 2;
  unsigned short* h = (unsigned short*)w;   w += (size_t)MAXROWS * FDIM * 2;

  hipMemsetAsync(d_out, 0, (size_t)out_size * 4, stream);
  hipMemsetAsync(perm, 0, (size_t)MAXROWS * 8, stream);  // perm + pwgt (adjacent)

  router_kernel<<<N_TOK, 64, 0, stream>>>(x, wgate, probs, eids, ewts);
  plan_kernel<<<1, 256, 0, stream>>>(probs, eids, out + 4194304, meta);
  scatter_kernel<<<16, 256, 0, stream>>>(eids, ewts, meta, perm, pwgt);
  convert_x_kernel<<<4096, 256, 0, stream>>>(x, xb);
  transpose_conv<<<dim3(64, 16, 8), 256, 0, stream>>>(w1, w1t, DDIM, FDIM);
  transpose_conv<<<dim3(16, 64, 8), 256, 0, stream>>>(w2, w2t, FDIM, DDIM);
  // GEMM1: rows x [1024] @ [1024 x 4096]/expert -> h (gelu, bf16). 40x16 panels.
  gemm2p<DDIM, 1, 16, true, 1><<<MAXT * 16, 512, 0, stream>>>(
      xb, w1t, h, nullptr, perm, pwgt, meta + 24, meta + 96, FDIM);
  // GEMM2: rows x [4096] @ [4096 x 1024]/expert, split-K=4 -> atomic f32 out.
  gemm2p<FDIM, 4, 4, false, 2><<<MAXT * 16, 512, 0, stream>>>(
      h, w2t, nullptr, out, perm, pwgt, meta + 24, meta + 96, DDIM);
}

// Round 6
// 401.876 us; speedup vs baseline: 1.9875x; 1.7782x over previous
//
#include <hip/hip_runtime.h>
#include <cmath>

#define N_TOK 4096
#define DDIM 1024
#define FDIM 4096
#define NEXP 8
#define MAXT 72
#define MAXROWS (MAXT * 128)

typedef __attribute__((ext_vector_type(4))) float f32x4;
typedef __attribute__((ext_vector_type(8))) __bf16 bf16x8;
typedef __attribute__((ext_vector_type(4))) unsigned short us4;
typedef __attribute__((ext_vector_type(8))) unsigned short us8;

__device__ __forceinline__ unsigned short f2bf(float f) {
  unsigned u = __builtin_bit_cast(unsigned, f);
  u += 0x7FFFu + ((u >> 16) & 1u);
  return (unsigned short)(u >> 16);
}

__device__ __forceinline__ void gload16(const void* g, void* l) {
  __builtin_amdgcn_global_load_lds(
      (const __attribute__((address_space(1))) unsigned int*)g,
      (__attribute__((address_space(3))) unsigned int*)l, 16, 0, 0);
}

// ---------------- router: logits -> softmax -> top2 ----------------
__global__ __launch_bounds__(64) void router_kernel(
    const float* __restrict__ x, const float* __restrict__ wg,
    float* __restrict__ probs, int* __restrict__ eids, float* __restrict__ ewts) {
  int n = blockIdx.x;
  int t = threadIdx.x;
  const float* xr = x + (size_t)n * DDIM;
  float acc[8] = {0, 0, 0, 0, 0, 0, 0, 0};
  for (int k = t; k < DDIM; k += 64) {
    float xv = xr[k];
    const float* wr = wg + k * 8;
#pragma unroll
    for (int e = 0; e < 8; e++) acc[e] = fmaf(xv, wr[e], acc[e]);
  }
#pragma unroll
  for (int off = 32; off > 0; off >>= 1) {
#pragma unroll
    for (int e = 0; e < 8; e++) acc[e] += __shfl_xor(acc[e], off, 64);
  }
  if (t == 0) {
    float mx = acc[0];
#pragma unroll
    for (int e = 1; e < 8; e++) mx = fmaxf(mx, acc[e]);
    float p[8], s = 0.f;
#pragma unroll
    for (int e = 0; e < 8; e++) { p[e] = expf(acc[e] - mx); s += p[e]; }
    float inv = 1.f / s;
#pragma unroll
    for (int e = 0; e < 8; e++) { p[e] *= inv; probs[n * 8 + e] = p[e]; }
    int i0 = 0;
#pragma unroll
    for (int e = 1; e < 8; e++) if (p[e] > p[i0]) i0 = e;
    int i1 = (i0 == 0) ? 1 : 0;
#pragma unroll
    for (int e = 0; e < 8; e++) if (e != i0 && p[e] > p[i1]) i1 = e;
    float sw = p[i0] + p[i1];
    eids[n * 2] = i0; eids[n * 2 + 1] = i1;
    ewts[n * 2] = p[i0] / sw; ewts[n * 2 + 1] = p[i1] / sw;
  }
}

// ---------------- plan: counts, psum, tile table, aux loss ----------------
// meta: [0..8) cnt, [8..16) cursor, [16..24) tileBase, [24..96) tileExpert, [96] total
__global__ __launch_bounds__(256) void plan_kernel(
    const float* __restrict__ probs, const int* __restrict__ eids,
    float* __restrict__ aux_out, int* __restrict__ meta) {
  __shared__ float pl[256][8];
  __shared__ int cl[256][8];
  __shared__ float ps2[8];
  __shared__ int cn2[8];
  int t = threadIdx.x;
  float pa[8] = {0, 0, 0, 0, 0, 0, 0, 0};
  int ca[8] = {0, 0, 0, 0, 0, 0, 0, 0};
  for (int n = t; n < N_TOK; n += 256) {
#pragma unroll
    for (int e = 0; e < 8; e++) pa[e] += probs[n * 8 + e];
    ca[eids[n * 2]]++; ca[eids[n * 2 + 1]]++;
  }
#pragma unroll
  for (int e = 0; e < 8; e++) { pl[t][e] = pa[e]; cl[t][e] = ca[e]; }
  __syncthreads();
  if (t < 8) {
    float s = 0; int c = 0;
    for (int i = 0; i < 256; i++) { s += pl[i][t]; c += cl[i][t]; }
    ps2[t] = s; cn2[t] = c;
  }
  __syncthreads();
  if (t == 0) {
    int tb = 0; float aux = 0.f;
    for (int e = 0; e < 8; e++) {
      int c = cn2[e];
      meta[e] = c; meta[8 + e] = 0; meta[16 + e] = tb;
      int tiles = (c + 127) >> 7;
      for (int i = 0; i < tiles; i++) meta[24 + tb + i] = e;
      tb += tiles;
      aux += ((float)c / (float)(N_TOK * 2)) * (ps2[e] / (float)N_TOK);
    }
    meta[96] = tb;
    *aux_out = 0.01f * 8.f * aux;
  }
}

// ---------------- scatter tokens into expert-grouped rows + inverse map ----------------
__global__ __launch_bounds__(256) void scatter_kernel(
    const int* __restrict__ eids, int* __restrict__ meta,
    int* __restrict__ perm, int* __restrict__ inv) {
  int n = blockIdx.x * 256 + threadIdx.x;
  if (n >= N_TOK) return;
#pragma unroll
  for (int s = 0; s < 2; s++) {
    int e = eids[n * 2 + s];
    int pos = atomicAdd(&meta[8 + e], 1);
    int row = (meta[16 + e] << 7) + pos;
    perm[row] = n;
    inv[n * 2 + s] = row;
  }
}

// ---------------- x f32 -> bf16 ----------------
__global__ __launch_bounds__(256) void convert_x_kernel(
    const float* __restrict__ x, unsigned short* __restrict__ xb) {
  int i = blockIdx.x * 256 + threadIdx.x;
  f32x4 v = ((const f32x4*)x)[i];
  us4 o = {f2bf(v[0]), f2bf(v[1]), f2bf(v[2]), f2bf(v[3])};
  ((us4*)xb)[i] = o;
}

// ---------------- transpose + convert: src f32 [R][C] -> dst bf16 [C][R] ----------------
__global__ __launch_bounds__(256) void transpose_conv(
    const float* __restrict__ src, unsigned short* __restrict__ dst, int R, int C) {
  __shared__ unsigned short tile[64 * 64];  // XOR-swizzled 16B chunks
  size_t eoff = (size_t)blockIdx.z * (size_t)R * (size_t)C;
  src += eoff; dst += eoff;
  int c0 = blockIdx.x << 6, r0 = blockIdx.y << 6;
  int t = threadIdx.x;
  int rl = (t >> 4) << 2;
  int cl = (t & 15) << 2;
  f32x4 v[4];
#pragma unroll
  for (int i = 0; i < 4; i++)
    v[i] = *(const f32x4*)(src + (size_t)(r0 + rl + i) * C + c0 + cl);
#pragma unroll
  for (int u = 0; u < 4; u++) {
    int c = cl + u;
    us4 o = {f2bf(v[0][u]), f2bf(v[1][u]), f2bf(v[2][u]), f2bf(v[3][u])};
    unsigned byteoff = (unsigned)c * 128 + ((((unsigned)(rl >> 3)) ^ (unsigned)(c & 7)) << 4) + (unsigned)(rl & 7) * 2;
    *(us4*)((char*)tile + byteoff) = o;
  }
  __syncthreads();
#pragma unroll
  for (int p = 0; p < 2; p++) {
    int id = t + p * 256;
    int c = id >> 3, q = id & 7;
    unsigned byteoff = (unsigned)c * 128 + (((unsigned)q ^ (unsigned)(c & 7)) << 4);
    us8 val = *(const us8*)((const char*)tile + byteoff);
    *(us8*)(dst + (size_t)(c0 + c) * R + r0 + q * 8) = val;
  }
}

// ---------------- grouped GEMM: 128x128 tile, BK=64, 16x16x32 bf16 MFMA ----------------
// (round-1 structure: best measured). MODE 1: gelu -> bf16 h store.
// MODE 2: plain f32 store of UNWEIGHTED y rows to scratch (no atomics).
template <int K, bool GATHER, int MODE>
__global__ __launch_bounds__(256, 2) void gemm_kernel(
    const unsigned short* __restrict__ A,   // bf16 rows, stride K
    const unsigned short* __restrict__ Bt,  // bf16 [E][NB][K]
    unsigned short* __restrict__ Hout,
    float* __restrict__ Out,
    const int* __restrict__ perm,
    const int* __restrict__ tileExpert, const int* __restrict__ totalTiles,
    int NB) {
  __shared__ unsigned short ldsA[128 * 64];
  __shared__ unsigned short ldsB[128 * 64];
  int tile = blockIdx.x;
  if (tile >= *totalTiles) return;
  int e = tileExpert[tile];
  int m0 = tile << 7;
  int n0 = blockIdx.y << 7;
  const unsigned short* Bbase = Bt + ((size_t)e * NB + n0) * K;
  int t = threadIdx.x;
  int wave = t >> 6, lane = t & 63;
  int g = lane >> 4, ln = lane & 15;
  int wm = wave >> 1, wn = wave & 1;

  const unsigned short* srcA[4];
  const unsigned short* srcB[4];
#pragma unroll
  for (int i = 0; i < 4; i++) {
    int c = wave * 256 + i * 64 + lane;
    int r = c >> 3, kc = c & 7;
    int rowA = GATHER ? perm[m0 + r] : (m0 + r);
    srcA[i] = A + (size_t)rowA * K + ((kc ^ (r & 7)) << 3);
    srcB[i] = Bbase + (size_t)r * K + ((kc ^ (r & 7)) << 3);
  }

  f32x4 acc[4][4];
#pragma unroll
  for (int a = 0; a < 4; a++)
#pragma unroll
    for (int b = 0; b < 4; b++) acc[a][b] = (f32x4){0.f, 0.f, 0.f, 0.f};

  for (int k0 = 0; k0 < K; k0 += 64) {
#pragma unroll
    for (int i = 0; i < 4; i++) {
      int cb = wave * 256 + i * 64;
      gload16(srcA[i] + k0, &ldsA[cb * 8]);
      gload16(srcB[i] + k0, &ldsB[cb * 8]);
    }
    __syncthreads();
#pragma unroll
    for (int ks = 0; ks < 2; ks++) {
      bf16x8 af[4], bfr[4];
      int q = ks * 4 + g;
#pragma unroll
      for (int mf = 0; mf < 4; mf++) {
        int m = wm * 64 + mf * 16 + ln;
        af[mf] = *(const bf16x8*)((const char*)ldsA + m * 128 + ((q ^ (m & 7)) << 4));
      }
#pragma unroll
      for (int nf = 0; nf < 4; nf++) {
        int n = wn * 64 + nf * 16 + ln;
        bfr[nf] = *(const bf16x8*)((const char*)ldsB + n * 128 + ((q ^ (n & 7)) << 4));
      }
#pragma unroll
      for (int mf = 0; mf < 4; mf++)
#pragma unroll
        for (int nf = 0; nf < 4; nf++)
          acc[mf][nf] = __builtin_amdgcn_mfma_f32_16x16x32_bf16(af[mf], bfr[nf], acc[mf][nf], 0, 0, 0);
    }
    __syncthreads();
  }

  if (MODE == 1) {
#pragma unroll
    for (int mf = 0; mf < 4; mf++) {
#pragma unroll
      for (int r = 0; r < 4; r++) {
        int row = m0 + wm * 64 + mf * 16 + g * 4 + r;
        unsigned short* hp = Hout + (size_t)row * NB + n0 + wn * 64 + ln;
#pragma unroll
        for (int nf = 0; nf < 4; nf++) {
          float v = acc[mf][nf][r];
          v = 0.5f * v * (1.f + erff(v * 0.70710678118654752f));
          hp[nf * 16] = f2bf(v);
        }
      }
    }
  } else {
#pragma unroll
    for (int mf = 0; mf < 4; mf++) {
#pragma unroll
      for (int r = 0; r < 4; r++) {
        int row = m0 + wm * 64 + mf * 16 + g * 4 + r;
        float* yp = Out + (size_t)row * NB + n0 + wn * 64 + ln;
#pragma unroll
        for (int nf = 0; nf < 4; nf++) yp[nf * 16] = acc[mf][nf][r];
      }
    }
  }
}

// ---------------- combine: out[n] = w0*y[r0] + w1*y[r1] ----------------
__global__ __launch_bounds__(256) void combine_kernel(
    const float* __restrict__ yscr, const int* __restrict__ inv,
    const float* __restrict__ ewts, float* __restrict__ out) {
  int n = blockIdx.x, t = threadIdx.x;
  int r0 = inv[n * 2], r1 = inv[n * 2 + 1];
  float w0 = ewts[n * 2], w1 = ewts[n * 2 + 1];
  f32x4 a = *(const f32x4*)(yscr + (size_t)r0 * DDIM + t * 4);
  f32x4 b = *(const f32x4*)(yscr + (size_t)r1 * DDIM + t * 4);
  f32x4 o;
#pragma unroll
  for (int j = 0; j < 4; j++) o[j] = w0 * a[j] + w1 * b[j];
  *(f32x4*)(out + (size_t)n * DDIM + t * 4) = o;
}

extern "C" void kernel_launch(void* const* d_in, const int* in_sizes, int n_in,
                              void* d_out, int out_size, void* d_ws, size_t ws_size,
                              hipStream_t stream) {
  const float* x = (const float*)d_in[0];
  const float* wgate = (const float*)d_in[1];
  const float* w1 = (const float*)d_in[2];
  const float* w2 = (const float*)d_in[3];
  float* out = (float*)d_out;

  char* w = (char*)d_ws;
  float* probs = (float*)w;                 w += (size_t)N_TOK * 8 * 4;
  int* eids = (int*)w;                      w += (size_t)N_TOK * 2 * 4;
  float* ewts = (float*)w;                  w += (size_t)N_TOK * 2 * 4;
  int* meta = (int*)w;                      w += 512;
  int* perm = (int*)w;                      w += (size_t)MAXROWS * 4;
  int* inv = (int*)w;                       w += (size_t)N_TOK * 2 * 4;
  unsigned short* xb = (unsigned short*)w;  w += (size_t)N_TOK * DDIM * 2;
  unsigned short* w1t = (unsigned short*)w; w += (size_t)NEXP * DDIM * FDIM * 2;
  unsigned short* w2t = (unsigned short*)w; w += (size_t)NEXP * DDIM * FDIM * 2;
  unsigned short* h = (unsigned short*)w;   w += (size_t)MAXROWS * FDIM * 2;
  // y scratch (MAXROWS x DDIM f32 = 37.75 MB) reuses the w1t region (64 MB),
  // which is dead after GEMM1; rewritten by transpose_conv every replay.
  float* yscr = (float*)w1t;

  hipMemsetAsync(perm, 0, (size_t)MAXROWS * 4, stream);  // padding rows -> token 0

  router_kernel<<<N_TOK, 64, 0, stream>>>(x, wgate, probs, eids, ewts);
  plan_kernel<<<1, 256, 0, stream>>>(probs, eids, out + 4194304, meta);
  scatter_kernel<<<16, 256, 0, stream>>>(eids, meta, perm, inv);
  convert_x_kernel<<<4096, 256, 0, stream>>>(x, xb);
  transpose_conv<<<dim3(64, 16, 8), 256, 0, stream>>>(w1, w1t, DDIM, FDIM);
  transpose_conv<<<dim3(16, 64, 8), 256, 0, stream>>>(w2, w2t, FDIM, DDIM);
  // GEMM1: gathered rows x [1024] @ [1024 x 4096]/expert -> h (gelu, bf16)
  gemm_kernel<DDIM, true, 1><<<dim3(MAXT, 32), 256, 0, stream>>>(
      xb, w1t, h, nullptr, perm, meta + 24, meta + 96, FDIM);
  // GEMM2: rows x [4096] @ [4096 x 1024]/expert -> yscr (plain f32 stores)
  gemm_kernel<FDIM, false, 2><<<dim3(MAXT, 8), 256, 0, stream>>>(
      h, w2t, nullptr, yscr, perm, meta + 24, meta + 96, DDIM);
  // weighted top-2 combine (deterministic, replaces atomic scatter)
  combine_kernel<<<N_TOK, 256, 0, stream>>>(yscr, inv, ewts, out);
}

// Round 7
// 385.271 us; speedup vs baseline: 2.0732x; 1.0431x over previous
//
#include <hip/hip_runtime.h>
#include <cmath>

#define N_TOK 4096
#define DDIM 1024
#define FDIM 4096
#define NEXP 8
#define MAXT 72
#define MAXROWS (MAXT * 128)

typedef __attribute__((ext_vector_type(4))) float f32x4;
typedef __attribute__((ext_vector_type(8))) __bf16 bf16x8;
typedef __attribute__((ext_vector_type(4))) unsigned short us4;
typedef __attribute__((ext_vector_type(8))) unsigned short us8;

__device__ __forceinline__ unsigned short f2bf(float f) {
  unsigned u = __builtin_bit_cast(unsigned, f);
  u += 0x7FFFu + ((u >> 16) & 1u);
  return (unsigned short)(u >> 16);
}

__device__ __forceinline__ void gload16(const void* g, void* l) {
  __builtin_amdgcn_global_load_lds(
      (const __attribute__((address_space(1))) unsigned int*)g,
      (__attribute__((address_space(3))) unsigned int*)l, 16, 0, 0);
}

// m204 bijective XCD remap: hw id (round-robin over 8 XCDs) -> logical id so
// each XCD owns a contiguous logical chunk.
__device__ __forceinline__ int xcd_remap(int h, int nwg) {
  int q = nwg >> 3, r = nwg & 7;
  int xcd = h & 7, o = h >> 3;
  return (xcd < r ? xcd * (q + 1) : r * (q + 1) + (xcd - r) * q) + o;
}

// ---------------- router: logits -> softmax -> top2 ----------------
__global__ __launch_bounds__(64) void router_kernel(
    const float* __restrict__ x, const float* __restrict__ wg,
    float* __restrict__ probs, int* __restrict__ eids, float* __restrict__ ewts) {
  int n = blockIdx.x;
  int t = threadIdx.x;
  const float* xr = x + (size_t)n * DDIM;
  float acc[8] = {0, 0, 0, 0, 0, 0, 0, 0};
  for (int k = t; k < DDIM; k += 64) {
    float xv = xr[k];
    const float* wr = wg + k * 8;
#pragma unroll
    for (int e = 0; e < 8; e++) acc[e] = fmaf(xv, wr[e], acc[e]);
  }
#pragma unroll
  for (int off = 32; off > 0; off >>= 1) {
#pragma unroll
    for (int e = 0; e < 8; e++) acc[e] += __shfl_xor(acc[e], off, 64);
  }
  if (t == 0) {
    float mx = acc[0];
#pragma unroll
    for (int e = 1; e < 8; e++) mx = fmaxf(mx, acc[e]);
    float p[8], s = 0.f;
#pragma unroll
    for (int e = 0; e < 8; e++) { p[e] = expf(acc[e] - mx); s += p[e]; }
    float inv = 1.f / s;
#pragma unroll
    for (int e = 0; e < 8; e++) { p[e] *= inv; probs[n * 8 + e] = p[e]; }
    int i0 = 0;
#pragma unroll
    for (int e = 1; e < 8; e++) if (p[e] > p[i0]) i0 = e;
    int i1 = (i0 == 0) ? 1 : 0;
#pragma unroll
    for (int e = 0; e < 8; e++) if (e != i0 && p[e] > p[i1]) i1 = e;
    float sw = p[i0] + p[i1];
    eids[n * 2] = i0; eids[n * 2 + 1] = i1;
    ewts[n * 2] = p[i0] / sw; ewts[n * 2 + 1] = p[i1] / sw;
  }
}

// ---------------- plan: counts, psum, tile table, aux loss ----------------
// meta: [0..8) cnt, [8..16) cursor, [16..24) tileBase, [24..96) tileExpert, [96] total
__global__ __launch_bounds__(256) void plan_kernel(
    const float* __restrict__ probs, const int* __restrict__ eids,
    float* __restrict__ aux_out, int* __restrict__ meta) {
  __shared__ float pl[256][8];
  __shared__ int cl[256][8];
  __shared__ float ps2[8];
  __shared__ int cn2[8];
  int t = threadIdx.x;
  float pa[8] = {0, 0, 0, 0, 0, 0, 0, 0};
  int ca[8] = {0, 0, 0, 0, 0, 0, 0, 0};
  for (int n = t; n < N_TOK; n += 256) {
#pragma unroll
    for (int e = 0; e < 8; e++) pa[e] += probs[n * 8 + e];
    ca[eids[n * 2]]++; ca[eids[n * 2 + 1]]++;
  }
#pragma unroll
  for (int e = 0; e < 8; e++) { pl[t][e] = pa[e]; cl[t][e] = ca[e]; }
  __syncthreads();
  if (t < 8) {
    float s = 0; int c = 0;
    for (int i = 0; i < 256; i++) { s += pl[i][t]; c += cl[i][t]; }
    ps2[t] = s; cn2[t] = c;
  }
  __syncthreads();
  if (t == 0) {
    int tb = 0; float aux = 0.f;
    for (int e = 0; e < 8; e++) {
      int c = cn2[e];
      meta[e] = c; meta[8 + e] = 0; meta[16 + e] = tb;
      int tiles = (c + 127) >> 7;
      for (int i = 0; i < tiles; i++) meta[24 + tb + i] = e;
      tb += tiles;
      aux += ((float)c / (float)(N_TOK * 2)) * (ps2[e] / (float)N_TOK);
    }
    meta[96] = tb;
    *aux_out = 0.01f * 8.f * aux;
  }
}

// ---------------- scatter tokens into expert-grouped rows + inverse map ----------------
__global__ __launch_bounds__(256) void scatter_kernel(
    const int* __restrict__ eids, int* __restrict__ meta,
    int* __restrict__ perm, int* __restrict__ inv) {
  int n = blockIdx.x * 256 + threadIdx.x;
  if (n >= N_TOK) return;
#pragma unroll
  for (int s = 0; s < 2; s++) {
    int e = eids[n * 2 + s];
    int pos = atomicAdd(&meta[8 + e], 1);
    int row = (meta[16 + e] << 7) + pos;
    perm[row] = n;
    inv[n * 2 + s] = row;
  }
}

// ---------------- x f32 -> bf16 ----------------
__global__ __launch_bounds__(256) void convert_x_kernel(
    const float* __restrict__ x, unsigned short* __restrict__ xb) {
  int i = blockIdx.x * 256 + threadIdx.x;
  f32x4 v = ((const f32x4*)x)[i];
  us4 o = {f2bf(v[0]), f2bf(v[1]), f2bf(v[2]), f2bf(v[3])};
  ((us4*)xb)[i] = o;
}

// ---------------- transpose + convert: src f32 [R][C] -> dst bf16 [C][R] ----------------
__global__ __launch_bounds__(256) void transpose_conv(
    const float* __restrict__ src, unsigned short* __restrict__ dst, int R, int C) {
  __shared__ unsigned short tile[64 * 64];  // XOR-swizzled 16B chunks
  size_t eoff = (size_t)blockIdx.z * (size_t)R * (size_t)C;
  src += eoff; dst += eoff;
  int c0 = blockIdx.x << 6, r0 = blockIdx.y << 6;
  int t = threadIdx.x;
  int rl = (t >> 4) << 2;
  int cl = (t & 15) << 2;
  f32x4 v[4];
#pragma unroll
  for (int i = 0; i < 4; i++)
    v[i] = *(const f32x4*)(src + (size_t)(r0 + rl + i) * C + c0 + cl);
#pragma unroll
  for (int u = 0; u < 4; u++) {
    int c = cl + u;
    us4 o = {f2bf(v[0][u]), f2bf(v[1][u]), f2bf(v[2][u]), f2bf(v[3][u])};
    unsigned byteoff = (unsigned)c * 128 + ((((unsigned)(rl >> 3)) ^ (unsigned)(c & 7)) << 4) + (unsigned)(rl & 7) * 2;
    *(us4*)((char*)tile + byteoff) = o;
  }
  __syncthreads();
#pragma unroll
  for (int p = 0; p < 2; p++) {
    int id = t + p * 256;
    int c = id >> 3, q = id & 7;
    unsigned byteoff = (unsigned)c * 128 + (((unsigned)q ^ (unsigned)(c & 7)) << 4);
    us8 val = *(const us8*)((const char*)tile + byteoff);
    *(us8*)(dst + (size_t)(c0 + c) * R + r0 + q * 8) = val;
  }
}

// ---------------- grouped GEMM: 128x128 tile, BK=64, 16x16x32 bf16 MFMA ----------------
// r6 structure + 1-D grid with XCD-chunked (m204) 8mt x 4nt supertiles:
// per supertile working set = 8 A-tiles (2 MB) + <=8 B-panels (2 MB) fits the
// 4 MB per-XCD L2. MODE 1: gelu -> bf16 h. MODE 2: plain f32 y store (no atomics).
template <int K, int NPANELS, bool GATHER, int MODE>
__global__ __launch_bounds__(256, 2) void gemm_kernel(
    const unsigned short* __restrict__ A,   // bf16 rows, stride K
    const unsigned short* __restrict__ Bt,  // bf16 [E][NB][K]
    unsigned short* __restrict__ Hout,
    float* __restrict__ Out,
    const int* __restrict__ perm,
    const int* __restrict__ tileExpert, const int* __restrict__ totalTiles,
    int NB) {
  __shared__ unsigned short ldsA[128 * 64];
  __shared__ unsigned short ldsB[128 * 64];
  constexpr int NWG = MAXT * NPANELS;
  int L = xcd_remap((int)blockIdx.x, NWG);
  int sup = L >> 5, wi = L & 31;          // 8mt x 4nt supertile, mt fastest
  constexpr int GM = MAXT / 8;            // 9
  int gm = sup % GM, gn = sup / GM;
  int tile = gm * 8 + (wi & 7);
  int nt = gn * 4 + (wi >> 3);
  if (tile >= *totalTiles) return;
  int e = tileExpert[tile];
  int m0 = tile << 7;
  int n0 = nt << 7;
  const unsigned short* Bbase = Bt + ((size_t)e * NB + n0) * K;
  int t = threadIdx.x;
  int wave = t >> 6, lane = t & 63;
  int g = lane >> 4, ln = lane & 15;
  int wm = wave >> 1, wn = wave & 1;

  const unsigned short* srcA[4];
  const unsigned short* srcB[4];
#pragma unroll
  for (int i = 0; i < 4; i++) {
    int c = wave * 256 + i * 64 + lane;
    int r = c >> 3, kc = c & 7;
    int rowA = GATHER ? perm[m0 + r] : (m0 + r);
    srcA[i] = A + (size_t)rowA * K + ((kc ^ (r & 7)) << 3);
    srcB[i] = Bbase + (size_t)r * K + ((kc ^ (r & 7)) << 3);
  }

  f32x4 acc[4][4];
#pragma unroll
  for (int a = 0; a < 4; a++)
#pragma unroll
    for (int b = 0; b < 4; b++) acc[a][b] = (f32x4){0.f, 0.f, 0.f, 0.f};

  for (int k0 = 0; k0 < K; k0 += 64) {
#pragma unroll
    for (int i = 0; i < 4; i++) {
      int cb = wave * 256 + i * 64;
      gload16(srcA[i] + k0, &ldsA[cb * 8]);
      gload16(srcB[i] + k0, &ldsB[cb * 8]);
    }
    __syncthreads();
#pragma unroll
    for (int ks = 0; ks < 2; ks++) {
      bf16x8 af[4], bfr[4];
      int q = ks * 4 + g;
#pragma unroll
      for (int mf = 0; mf < 4; mf++) {
        int m = wm * 64 + mf * 16 + ln;
        af[mf] = *(const bf16x8*)((const char*)ldsA + m * 128 + ((q ^ (m & 7)) << 4));
      }
#pragma unroll
      for (int nf = 0; nf < 4; nf++) {
        int n = wn * 64 + nf * 16 + ln;
        bfr[nf] = *(const bf16x8*)((const char*)ldsB + n * 128 + ((q ^ (n & 7)) << 4));
      }
#pragma unroll
      for (int mf = 0; mf < 4; mf++)
#pragma unroll
        for (int nf = 0; nf < 4; nf++)
          acc[mf][nf] = __builtin_amdgcn_mfma_f32_16x16x32_bf16(af[mf], bfr[nf], acc[mf][nf], 0, 0, 0);
    }
    __syncthreads();
  }

  if (MODE == 1) {
#pragma unroll
    for (int mf = 0; mf < 4; mf++) {
#pragma unroll
      for (int r = 0; r < 4; r++) {
        int row = m0 + wm * 64 + mf * 16 + g * 4 + r;
        unsigned short* hp = Hout + (size_t)row * NB + n0 + wn * 64 + ln;
#pragma unroll
        for (int nf = 0; nf < 4; nf++) {
          float v = acc[mf][nf][r];
          v = 0.5f * v * (1.f + erff(v * 0.70710678118654752f));
          hp[nf * 16] = f2bf(v);
        }
      }
    }
  } else {
#pragma unroll
    for (int mf = 0; mf < 4; mf++) {
#pragma unroll
      for (int r = 0; r < 4; r++) {
        int row = m0 + wm * 64 + mf * 16 + g * 4 + r;
        float* yp = Out + (size_t)row * NB + n0 + wn * 64 + ln;
#pragma unroll
        for (int nf = 0; nf < 4; nf++) yp[nf * 16] = acc[mf][nf][r];
      }
    }
  }
}

// ---------------- combine: out[n] = w0*y[r0] + w1*y[r1] ----------------
__global__ __launch_bounds__(256) void combine_kernel(
    const float* __restrict__ yscr, const int* __restrict__ inv,
    const float* __restrict__ ewts, float* __restrict__ out) {
  int n = blockIdx.x, t = threadIdx.x;
  int r0 = inv[n * 2], r1 = inv[n * 2 + 1];
  float w0 = ewts[n * 2], w1 = ewts[n * 2 + 1];
  f32x4 a = *(const f32x4*)(yscr + (size_t)r0 * DDIM + t * 4);
  f32x4 b = *(const f32x4*)(yscr + (size_t)r1 * DDIM + t * 4);
  f32x4 o;
#pragma unroll
  for (int j = 0; j < 4; j++) o[j] = w0 * a[j] + w1 * b[j];
  *(f32x4*)(out + (size_t)n * DDIM + t * 4) = o;
}

extern "C" void kernel_launch(void* const* d_in, const int* in_sizes, int n_in,
                              void* d_out, int out_size, void* d_ws, size_t ws_size,
                              hipStream_t stream) {
  const float* x = (const float*)d_in[0];
  const float* wgate = (const float*)d_in[1];
  const float* w1 = (const float*)d_in[2];
  const float* w2 = (const float*)d_in[3];
  float* out = (float*)d_out;

  char* w = (char*)d_ws;
  float* probs = (float*)w;                 w += (size_t)N_TOK * 8 * 4;
  int* eids = (int*)w;                      w += (size_t)N_TOK * 2 * 4;
  float* ewts = (float*)w;                  w += (size_t)N_TOK * 2 * 4;
  int* meta = (int*)w;                      w += 512;
  int* perm = (int*)w;                      w += (size_t)MAXROWS * 4;
  int* inv = (int*)w;                       w += (size_t)N_TOK * 2 * 4;
  unsigned short* xb = (unsigned short*)w;  w += (size_t)N_TOK * DDIM * 2;
  unsigned short* w1t = (unsigned short*)w; w += (size_t)NEXP * DDIM * FDIM * 2;
  unsigned short* w2t = (unsigned short*)w; w += (size_t)NEXP * DDIM * FDIM * 2;
  unsigned short* h = (unsigned short*)w;   w += (size_t)MAXROWS * FDIM * 2;
  // y scratch (MAXROWS x DDIM f32 = 37.75 MB) reuses the w1t region (64 MB),
  // which is dead after GEMM1; rewritten by transpose_conv every replay.
  float* yscr = (float*)w1t;

  hipMemsetAsync(perm, 0, (size_t)MAXROWS * 4, stream);  // padding rows -> token 0

  router_kernel<<<N_TOK, 64, 0, stream>>>(x, wgate, probs, eids, ewts);
  plan_kernel<<<1, 256, 0, stream>>>(probs, eids, out + 4194304, meta);
  scatter_kernel<<<16, 256, 0, stream>>>(eids, meta, perm, inv);
  convert_x_kernel<<<4096, 256, 0, stream>>>(x, xb);
  transpose_conv<<<dim3(64, 16, 8), 256, 0, stream>>>(w1, w1t, DDIM, FDIM);
  transpose_conv<<<dim3(16, 64, 8), 256, 0, stream>>>(w2, w2t, FDIM, DDIM);
  // GEMM1: gathered rows x [1024] @ [1024 x 4096]/expert -> h (gelu, bf16)
  gemm_kernel<DDIM, 32, true, 1><<<MAXT * 32, 256, 0, stream>>>(
      xb, w1t, h, nullptr, perm, meta + 24, meta + 96, FDIM);
  // GEMM2: rows x [4096] @ [4096 x 1024]/expert -> yscr (plain f32 stores)
  gemm_kernel<FDIM, 8, false, 2><<<MAXT * 8, 256, 0, stream>>>(
      h, w2t, nullptr, yscr, perm, meta + 24, meta + 96, DDIM);
  // weighted top-2 combine (deterministic, replaces atomic scatter)
  combine_kernel<<<N_TOK, 256, 0, stream>>>(yscr, inv, ewts, out);
}